// Round 1
// baseline (690.673 us; speedup 1.0000x reference)
//
#include <hip/hip_runtime.h>
#include <math.h>

// x:[2,256,256,512] f32 -> out:[2,256,128,256] f32
// Planes p = 2m (Re), 2m+1 (Im), m=0..127 (m=128 slice of wmat_hi is identically 0).

#define ROWS_HI 131072   // B*C*H_HI
#define ROWS_LO 65536    // B*C*H_LO

// ws byte offsets
#define B_FT    0LL           // F_T  bf16 [256 p][512 w]
#define B_FIT   262144LL      // Fi_T bf16 [256 w'][256 p]
#define B_WM    393216LL      // wmat bf16 [128 m][128 l][256 k]
#define B_PCT   8781824LL     // pctT bf16 [128 m][128 k'][128 l]
#define B_WB    12976128LL    // conv_w bf16 [256 o][256 c]
#define B_STATS 13107200LL    // 128 floats
#define B_R1    13107712LL    // 64 MB region: Xbf(64MB bf16) -> gb(32MB bf16) -> y(64MB f32)
#define B_R2    80216576LL    // 32 MB region: flmb -> gTb -> yT (all bf16)
// total 113,771,008 B

typedef __attribute__((ext_vector_type(8))) short bf16x8;
typedef __attribute__((ext_vector_type(8))) unsigned short ushort8;
typedef __attribute__((ext_vector_type(4))) unsigned short ushort4v;
typedef __attribute__((ext_vector_type(4))) float f32x4;

__device__ inline unsigned short f2bf(float f){
  unsigned int u = __float_as_uint(f);
  unsigned int r = u + 0x7FFFu + ((u >> 16) & 1u);
  return (unsigned short)(r >> 16);
}

// ---------------- tables: DFT/iDFT twiddles (bf16) + zero stats ---------------
__global__ __launch_bounds__(256) void k_tables(unsigned char* __restrict__ ws){
  unsigned short* FT  = (unsigned short*)(ws + B_FT);
  unsigned short* FIT = (unsigned short*)(ws + B_FIT);
  float* stats = (float*)(ws + B_STATS);
  int idx = blockIdx.x*256 + threadIdx.x;
  if (idx < 131072){            // F_T[p][w]
    int p = idx >> 9, w = idx & 511, m = p >> 1;
    int pr = (m*w) & 511;
    float ang = (float)pr * (float)(2.0*M_PI/512.0);
    float s, c; sincosf(ang, &s, &c);
    const float S = (float)(2.0*M_PI/512.0);
    FT[idx] = f2bf((p & 1) ? (-S*s) : (S*c));
  }
  int i2 = idx - 131072;
  if (i2 >= 0 && i2 < 65536){   // Fi_T[w'][p]
    int w = i2 >> 8, p = i2 & 255, m = p >> 1;
    float eps = (m == 0) ? 1.f : 2.f;
    int pr = (m*w) & 255;
    float ang = (float)pr * (float)(2.0*M_PI/256.0);
    float s, c; sincosf(ang, &s, &c);
    FIT[i2] = f2bf((p & 1) ? (-eps*s) : (eps*c));
  }
  int i3 = idx - (131072 + 65536);
  if (i3 >= 0 && i3 < 128) stats[i3] = 0.f;
}

// ------- prep: wmat->bf16, pct->bf16 transposed, conv_w->bf16 ----------------
__global__ __launch_bounds__(256) void k_prep(const float* __restrict__ wmat,
                                              const float* __restrict__ pct,
                                              const float* __restrict__ Wc,
                                              unsigned char* __restrict__ ws){
  unsigned short* WM = (unsigned short*)(ws + B_WM);
  unsigned short* PT = (unsigned short*)(ws + B_PCT);
  unsigned short* WB = (unsigned short*)(ws + B_WB);
  int idx = blockIdx.x*256 + threadIdx.x;
  if (idx < 4194304){
    WM[idx] = f2bf(wmat[idx]);            // [m][l][k] direct, m<128
  } else if (idx < 6291456){
    int j = idx - 4194304;                // pctT[m][kp][l] = pct[m][l][kp]
    int m = j >> 14, kp = (j >> 7) & 127, l = j & 127;
    PT[j] = f2bf(pct[m*16384 + l*128 + kp]);
  } else if (idx < 6356992){
    int j = idx - 6291456;
    WB[j] = f2bf(Wc[j]);                  // [o][c]
  }
}

// ---------------- MFMA GEMM template -----------------------------------------
// C[M][N] = A[M][K] * B_T[N][K]^T ; BM=MT*32, BN=NT*32, BK=32, 256 thr
// (2x2 waves, each wave (MT*16)x(NT*16) via 16x16x32 bf16 MFMA).
// AMODE 0: A fp32 -> quantize to bf16 in staging (BM 128 or 64)
// AMODE 1: A bf16 (pre-quantized)
// CMODE 0: row-major fp32 store (+optional bias[row])
// CMODE 1: transposed bf16 store C_T[col][row]
// CMODE 2: row-major bf16 store
// SKIP 1: skip nt-tiles with col_max < m (leg1, cols=l) ; SKIP 2: k-loop starts
//         at (m>>5) (leg2, k=l).  m = blockIdx.z>>1.
// WPE: min waves per EU hint (occupancy floor for the register allocator).
template<int AMODE, int CMODE, bool BIAS, int MT, int NT, int SKIP, int WPE>
__global__ __launch_bounds__(256, WPE) void k_gemm(
    const float* __restrict__ Af,
    const unsigned short* __restrict__ Abf,
    const unsigned short* __restrict__ Bt,
    float* __restrict__ Cf,
    unsigned short* __restrict__ Cbf,
    const float* __restrict__ bias,
    int ldA, int ldB, int ldC, int ksteps,
    long long sA, long long sB, int bzsh, long long sC)
{
  constexpr int BM = MT*32;
  constexpr int BN = NT*32;
  __shared__ unsigned short As[BM][40];
  __shared__ unsigned short Bs[BN][40];
  const int tid = threadIdx.x;
  const int z = blockIdx.z;
  const int m = z >> 1;
  const long long offA = (long long)z * sA;
  const long long offB = (long long)(z >> bzsh) * sB;
  const long long offC = (long long)z * sC;
  const int row0 = blockIdx.x * BM;
  const int n0   = blockIdx.y * BN;
  const int lane = tid & 63;
  const int wv = tid >> 6;
  const int wm = wv >> 1, wn = wv & 1;
  const int fr = lane & 15, q = lane >> 4;

  f32x4 acc[MT][NT];
#pragma unroll
  for (int i=0;i<MT;++i)
#pragma unroll
    for (int j=0;j<NT;++j) acc[i][j] = (f32x4){0.f,0.f,0.f,0.f};

  int ks0 = (SKIP == 2) ? (m >> 5) : 0;
  for (int ks = ks0; ks < ksteps; ++ks){
    const int k0 = ks * 32;
    // ---- stage A
    if (AMODE == 0){
      if (BM == 128){
        const int row = tid >> 1, half = tid & 1;
        const float* s = Af + offA + (long long)(row0 + row) * ldA + k0 + half*16;
        float vv[16];
        *(float4*)(vv+0)  = *(const float4*)(s+0);
        *(float4*)(vv+4)  = *(const float4*)(s+4);
        *(float4*)(vv+8)  = *(const float4*)(s+8);
        *(float4*)(vv+12) = *(const float4*)(s+12);
        ushort8 H0, H1;
#pragma unroll
        for (int j=0;j<8;++j){ H0[j] = f2bf(vv[j]); H1[j] = f2bf(vv[8+j]); }
        *(ushort8*)&As[row][half*16]   = H0;
        *(ushort8*)&As[row][half*16+8] = H1;
      } else { // BM == 64
        const int row = tid >> 2, qt = tid & 3;
        const float* s = Af + offA + (long long)(row0 + row) * ldA + k0 + qt*8;
        float vv[8];
        *(float4*)(vv+0) = *(const float4*)(s+0);
        *(float4*)(vv+4) = *(const float4*)(s+4);
        ushort8 H;
#pragma unroll
        for (int j=0;j<8;++j) H[j] = f2bf(vv[j]);
        *(ushort8*)&As[row][qt*8] = H;
      }
    } else if (BM == 256){
      const unsigned short* s = Abf + offA + (long long)(row0 + tid) * ldA + k0;
      *(ushort8*)&As[tid][0]  = *(const ushort8*)(s);
      *(ushort8*)&As[tid][8]  = *(const ushort8*)(s+8);
      *(ushort8*)&As[tid][16] = *(const ushort8*)(s+16);
      *(ushort8*)&As[tid][24] = *(const ushort8*)(s+24);
    } else if (BM == 128){
      const int row = tid >> 1, half = tid & 1;
      const unsigned short* s = Abf + offA + (long long)(row0 + row) * ldA + k0 + half*16;
      *(ushort8*)&As[row][half*16]   = *(const ushort8*)(s);
      *(ushort8*)&As[row][half*16+8] = *(const ushort8*)(s+8);
    } else { // BM == 64
      const int row = tid >> 2, qt = tid & 3;
      const unsigned short* s = Abf + offA + (long long)(row0 + row) * ldA + k0 + qt*8;
      *(ushort8*)&As[row][qt*8] = *(const ushort8*)(s);
    }
    // ---- stage B
    if (BN == 256){
      const unsigned short* s = Bt + offB + (long long)(n0 + tid) * ldB + k0;
      *(ushort8*)&Bs[tid][0]  = *(const ushort8*)(s);
      *(ushort8*)&Bs[tid][8]  = *(const ushort8*)(s+8);
      *(ushort8*)&Bs[tid][16] = *(const ushort8*)(s+16);
      *(ushort8*)&Bs[tid][24] = *(const ushort8*)(s+24);
    } else if (BN == 128){
      const int row = tid >> 1, half = tid & 1;
      const unsigned short* s = Bt + offB + (long long)(n0 + row) * ldB + k0 + half*16;
      *(ushort8*)&Bs[row][half*16]   = *(const ushort8*)(s);
      *(ushort8*)&Bs[row][half*16+8] = *(const ushort8*)(s+8);
    } else { // BN == 64
      const int row = tid >> 2, qt = tid & 3;
      const unsigned short* s = Bt + offB + (long long)(n0 + row) * ldB + k0 + qt*8;
      *(ushort8*)&Bs[row][qt*8] = *(const ushort8*)(s);
    }
    __syncthreads();
    bf16x8 ah[MT];
#pragma unroll
    for (int mt=0;mt<MT;++mt)
      ah[mt] = *(const bf16x8*)&As[wm*(MT*16)+mt*16+fr][q*8];
#pragma unroll
    for (int nt=0;nt<NT;++nt){
      if (SKIP == 1 && (wn*(NT*16) + nt*16 + 16 <= m)) continue;
      bf16x8 bb = *(const bf16x8*)&Bs[wn*(NT*16)+nt*16+fr][q*8];
#pragma unroll
      for (int mt=0;mt<MT;++mt)
        acc[mt][nt] = __builtin_amdgcn_mfma_f32_16x16x32_bf16(ah[mt], bb, acc[mt][nt], 0,0,0);
    }
    __syncthreads();
  }

  if (CMODE == 0){
#pragma unroll
    for (int mt=0;mt<MT;++mt){
      int row = row0 + wm*(MT*16) + mt*16 + q*4;
      float bv0=0.f,bv1=0.f,bv2=0.f,bv3=0.f;
      if (BIAS){ bv0=bias[row]; bv1=bias[row+1]; bv2=bias[row+2]; bv3=bias[row+3]; }
#pragma unroll
      for (int nt=0;nt<NT;++nt){
        int col = n0 + wn*(NT*16) + nt*16 + fr;
        float* dst = Cf + offC + (long long)row * ldC + col;
        dst[0]                = acc[mt][nt][0] + bv0;
        dst[(long long)ldC]   = acc[mt][nt][1] + bv1;
        dst[(long long)ldC*2] = acc[mt][nt][2] + bv2;
        dst[(long long)ldC*3] = acc[mt][nt][3] + bv3;
      }
    }
  } else if (CMODE == 1){
#pragma unroll
    for (int nt=0;nt<NT;++nt){
      int colp = n0 + wn*(NT*16) + nt*16 + fr;
#pragma unroll
      for (int mt=0;mt<MT;++mt){
        int rowb = row0 + wm*(MT*16) + mt*16 + q*4;
        ushort4v h;
        h[0] = f2bf(acc[mt][nt][0]);
        h[1] = f2bf(acc[mt][nt][1]);
        h[2] = f2bf(acc[mt][nt][2]);
        h[3] = f2bf(acc[mt][nt][3]);
        *(ushort4v*)&Cbf[offC + (long long)colp * ldC + rowb] = h;
      }
    }
  } else {
#pragma unroll
    for (int mt=0;mt<MT;++mt){
      int row = row0 + wm*(MT*16) + mt*16 + q*4;
#pragma unroll
      for (int nt=0;nt<NT;++nt){
        int col = n0 + wn*(NT*16) + nt*16 + fr;
        unsigned short* dst = Cbf + offC + (long long)row * ldC + col;
        dst[0]      = f2bf(acc[mt][nt][0]);
        dst[ldC]    = f2bf(acc[mt][nt][1]);
        dst[ldC*2]  = f2bf(acc[mt][nt][2]);
        dst[ldC*3]  = f2bf(acc[mt][nt][3]);
      }
    }
  }
}

// ------- transpose bf16 g[256 p][65536 r] -> gT[65536 r][256 p] ---------------
__global__ __launch_bounds__(256) void k_trb(const unsigned short* __restrict__ g,
                                             unsigned short* __restrict__ gT){
  __shared__ unsigned short t[64][68];
  const int r0 = blockIdx.x * 64;
  const int p0 = blockIdx.y * 64;
  const int tr = threadIdx.x & 15, tc = threadIdx.x >> 4;
#pragma unroll
  for (int i=0;i<4;++i){
    int pl = tc + i*16;
    ushort4v v = *(const ushort4v*)(g + (long long)(p0+pl)*ROWS_LO + r0 + tr*4);
    *(ushort4v*)&t[pl][tr*4] = v;
  }
  __syncthreads();
#pragma unroll
  for (int i=0;i<4;++i){
    int rl = tc + i*16;
    ushort4v w;
    w[0]=t[tr*4+0][rl]; w[1]=t[tr*4+1][rl]; w[2]=t[tr*4+2][rl]; w[3]=t[tr*4+3][rl];
    *(ushort4v*)(gT + (long long)(r0+rl)*256 + p0 + tr*4) = w;
  }
}

// ------- transpose y[b][256 c][32768 s] f32 -> yT[b][s][c] bf16 ---------------
__global__ __launch_bounds__(256) void k_tr2(const float* __restrict__ y,
                                             unsigned short* __restrict__ yT){
  __shared__ float t[64][65];
  const int s0 = blockIdx.x * 64;
  const int c0 = blockIdx.y * 64;
  const int b  = blockIdx.z;
  const int tr = threadIdx.x & 15, tc = threadIdx.x >> 4;
#pragma unroll
  for (int i=0;i<4;++i){
    int cl = tc + i*16;
    float4 v = *(const float4*)(y + (long long)b*8388608 + (long long)(c0+cl)*32768 + s0 + tr*4);
    t[cl][tr*4+0]=v.x; t[cl][tr*4+1]=v.y; t[cl][tr*4+2]=v.z; t[cl][tr*4+3]=v.w;
  }
  __syncthreads();
#pragma unroll
  for (int i=0;i<4;++i){
    int sl = tc + i*16;
    ushort4v w;
    w[0]=f2bf(t[tr*4+0][sl]); w[1]=f2bf(t[tr*4+1][sl]);
    w[2]=f2bf(t[tr*4+2][sl]); w[3]=f2bf(t[tr*4+3][sl]);
    *(ushort4v*)(yT + (long long)b*8388608 + (long long)(s0+sl)*256 + c0 + tr*4) = w;
  }
}

// ---------------- GroupNorm stats --------------------------------------------
__global__ __launch_bounds__(256) void k_stats(const float* __restrict__ h,
                                               float* __restrict__ stats){
  const int bg = blockIdx.y;
  const int j  = blockIdx.x;
  const int t  = threadIdx.x;
  const float* base = h + (long long)bg*262144 + j*8192;
  float s = 0.f, ss = 0.f;
#pragma unroll
  for (int i=0;i<8;++i){
    float4 v = *(const float4*)(base + i*1024 + t*4);
    s  += v.x + v.y + v.z + v.w;
    ss += v.x*v.x + v.y*v.y + v.z*v.z + v.w*v.w;
  }
#pragma unroll
  for (int off=32; off>0; off>>=1){
    s  += __shfl_down(s, off, 64);
    ss += __shfl_down(ss, off, 64);
  }
  __shared__ float red[8];
  int wid = t >> 6;
  if ((t & 63) == 0){ red[wid*2] = s; red[wid*2+1] = ss; }
  __syncthreads();
  if (t == 0){
    float S  = red[0]+red[2]+red[4]+red[6];
    float SS = red[1]+red[3]+red[5]+red[7];
    atomicAdd(&stats[bg*2+0], S);
    atomicAdd(&stats[bg*2+1], SS);
  }
}

// ---------------- normalize + affine + exact GELU ----------------------------
__global__ __launch_bounds__(256) void k_norm(float* __restrict__ out,
                                              const float* __restrict__ stats,
                                              const float* __restrict__ gamma,
                                              const float* __restrict__ beta){
  long long idx4 = ((long long)blockIdx.x*256 + threadIdx.x)*4;
  int o = (int)((idx4 >> 15) & 255);
  int b = (int)(idx4 >> 23);
  int bg = b*32 + (o >> 3);
  const float inv_n = 1.0f/262144.0f;
  float mean = stats[bg*2+0] * inv_n;
  float var  = stats[bg*2+1] * inv_n - mean*mean;
  float sc = rsqrtf(var + 1e-5f);
  float ga = gamma[o], be = beta[o];
  float4 v = *(float4*)(out + idx4);
  float t0 = (v.x - mean)*sc*ga + be;
  float t1 = (v.y - mean)*sc*ga + be;
  float t2 = (v.z - mean)*sc*ga + be;
  float t3 = (v.w - mean)*sc*ga + be;
  const float ISQ2 = 0.70710678118654752f;
  v.x = 0.5f*t0*(1.0f + erff(t0*ISQ2));
  v.y = 0.5f*t1*(1.0f + erff(t1*ISQ2));
  v.z = 0.5f*t2*(1.0f + erff(t2*ISQ2));
  v.w = 0.5f*t3*(1.0f + erff(t3*ISQ2));
  *(float4*)(out + idx4) = v;
}

extern "C" void kernel_launch(void* const* d_in, const int* in_sizes, int n_in,
                              void* d_out, int out_size, void* d_ws, size_t ws_size,
                              hipStream_t stream){
  const float* x      = (const float*)d_in[0];
  const float* conv_w = (const float*)d_in[1];
  const float* conv_b = (const float*)d_in[2];
  const float* gamma  = (const float*)d_in[3];
  const float* beta   = (const float*)d_in[4];
  const float* wmat   = (const float*)d_in[5];
  const float* pct    = (const float*)d_in[6];
  unsigned char* ws = (unsigned char*)d_ws;

  unsigned short* FT   = (unsigned short*)(ws + B_FT);
  unsigned short* FIT  = (unsigned short*)(ws + B_FIT);
  unsigned short* WM   = (unsigned short*)(ws + B_WM);
  unsigned short* PT   = (unsigned short*)(ws + B_PCT);
  unsigned short* WB   = (unsigned short*)(ws + B_WB);
  float*          stats= (float*)(ws + B_STATS);
  unsigned short* Xbf  = (unsigned short*)(ws + B_R1);  // [256 p][131072] bf16
  unsigned short* gb   = (unsigned short*)(ws + B_R1);  // [256 p][65536] bf16 (Xbf dead)
  float*          y    = (float*)(ws + B_R1);           // [65536][256] f32 (gb dead)
  unsigned short* flmb = (unsigned short*)(ws + B_R2);  // [256 p][512 bc][128 l] bf16
  unsigned short* gTb  = (unsigned short*)(ws + B_R2);  // [65536][256 p] bf16 (flmb dead)
  unsigned short* yT   = (unsigned short*)(ws + B_R2);  // [b][32768 s][256 c] bf16 (gTb dead)
  float* out = (float*)d_out;

  k_tables<<<769, 256, 0, stream>>>(ws);
  k_prep  <<<24832, 256, 0, stream>>>(wmat, pct, conv_w, ws);

  // DFT: A=x f32 [131072x512] (quantized in staging), B=F_T, C->Xbf trans bf16
  // BM=64 (MT=2) keeps acc at 64 regs -> >=3 waves/SIMD; x still read exactly once.
  k_gemm<0,1,false,2,8,0,3><<<dim3(2048,1,1), 256, 0, stream>>>(
      x, nullptr, FT, nullptr, Xbf, nullptr, 512, 512, ROWS_HI, 16, 0, 0, 0, 0);
  // Leg1: per plane: A=Xbf[p] [512x256], B=WM[m] [128lx256k], C=flmb bf16; skip l<m tiles
  k_gemm<1,2,false,4,4,1,1><<<dim3(4,1,256), 256, 0, stream>>>(
      nullptr, Xbf, WM, nullptr, flmb, nullptr, 256, 256, 128, 8,
      131072LL, 32768LL, 1, 65536LL);
  // Leg2: per plane: A=flmb[p] [512x128], B=PT[m] [128k'x128l], C=gb bf16; k-start m>>5
  k_gemm<1,2,false,4,4,2,1><<<dim3(4,1,256), 256, 0, stream>>>(
      nullptr, flmb, PT, nullptr, gb, nullptr, 128, 128, 128, 4,
      65536LL, 16384LL, 1, 65536LL);
  // transpose gb -> gTb
  k_trb<<<dim3(1024,4), 256, 0, stream>>>(gb, gTb);
  // iDFT: A=gTb [65536x256], B=Fi_T [256w'x256p], C=y f32  (BM=64, acc 64 regs)
  k_gemm<1,0,false,2,8,0,3><<<dim3(1024,1,1), 256, 0, stream>>>(
      nullptr, gTb, FIT, y, nullptr, nullptr, 256, 256, 256, 8, 0, 0, 0, 0);
  // transpose+quantize y -> yT bf16
  k_tr2<<<dim3(512,4,2), 256, 0, stream>>>(y, yT);
  // Conv: per b: A=WB [256x256], B=yT[b] [32768x256], C=out f32 +bias
  // BN=64 (NT=2) keeps acc at 64 regs; yT still read exactly once.
  k_gemm<1,0,true,8,2,0,3><<<dim3(1,512,2), 256, 0, stream>>>(
      nullptr, WB, yT, out, nullptr, conv_b, 256, 256, 32768, 8,
      0, 8388608LL, 0, 8388608LL);

  k_stats<<<dim3(32,64), 256, 0, stream>>>(out, stats);
  k_norm <<<16384, 256, 0, stream>>>(out, stats, gamma, beta);
}

// Round 2
// 634.978 us; speedup vs baseline: 1.0877x; 1.0877x over previous
//
#include <hip/hip_runtime.h>
#include <math.h>

// x:[2,256,256,512] f32 -> out:[2,256,128,256] f32
// Planes p = 2m (Re), 2m+1 (Im), m=0..127 (m=128 slice of wmat_hi is identically 0).

#define ROWS_HI 131072   // B*C*H_HI
#define ROWS_LO 65536    // B*C*H_LO

// ws byte offsets
#define B_FT    0LL           // F_T  bf16 [256 p][512 w]
#define B_FIT   262144LL      // Fi_T bf16 [256 w'][256 p]
#define B_WM    393216LL      // wmat bf16 [128 m][128 l][256 k]
#define B_PCT   8781824LL     // pctT bf16 [128 m][128 k'][128 l]
#define B_WB    12976128LL    // conv_w bf16 [256 o][256 c]
#define B_STATS 13107200LL    // 128 floats
#define B_R1    13107712LL    // 64 MB region: Xbf(64MB bf16) -> gb(32MB bf16) -> y(64MB f32)
#define B_R2    80216576LL    // 32 MB region: flmb -> gTb -> yT (all bf16)
// total 113,771,008 B

typedef __attribute__((ext_vector_type(8))) short bf16x8;
typedef __attribute__((ext_vector_type(8))) unsigned short ushort8;
typedef __attribute__((ext_vector_type(4))) unsigned short ushort4v;
typedef __attribute__((ext_vector_type(4))) float f32x4;

__device__ inline unsigned short f2bf(float f){
  unsigned int u = __float_as_uint(f);
  unsigned int r = u + 0x7FFFu + ((u >> 16) & 1u);
  return (unsigned short)(r >> 16);
}

// ---------------- tables: DFT/iDFT twiddles (bf16) + zero stats ---------------
__global__ __launch_bounds__(256) void k_tables(unsigned char* __restrict__ ws){
  unsigned short* FT  = (unsigned short*)(ws + B_FT);
  unsigned short* FIT = (unsigned short*)(ws + B_FIT);
  float* stats = (float*)(ws + B_STATS);
  int idx = blockIdx.x*256 + threadIdx.x;
  if (idx < 131072){            // F_T[p][w]
    int p = idx >> 9, w = idx & 511, m = p >> 1;
    int pr = (m*w) & 511;
    float ang = (float)pr * (float)(2.0*M_PI/512.0);
    float s, c; sincosf(ang, &s, &c);
    const float S = (float)(2.0*M_PI/512.0);
    FT[idx] = f2bf((p & 1) ? (-S*s) : (S*c));
  }
  int i2 = idx - 131072;
  if (i2 >= 0 && i2 < 65536){   // Fi_T[w'][p]
    int w = i2 >> 8, p = i2 & 255, m = p >> 1;
    float eps = (m == 0) ? 1.f : 2.f;
    int pr = (m*w) & 255;
    float ang = (float)pr * (float)(2.0*M_PI/256.0);
    float s, c; sincosf(ang, &s, &c);
    FIT[i2] = f2bf((p & 1) ? (-eps*s) : (eps*c));
  }
  int i3 = idx - (131072 + 65536);
  if (i3 >= 0 && i3 < 128) stats[i3] = 0.f;
}

// ------- prep: wmat->bf16, pct->bf16 transposed, conv_w->bf16 ----------------
__global__ __launch_bounds__(256) void k_prep(const float* __restrict__ wmat,
                                              const float* __restrict__ pct,
                                              const float* __restrict__ Wc,
                                              unsigned char* __restrict__ ws){
  unsigned short* WM = (unsigned short*)(ws + B_WM);
  unsigned short* PT = (unsigned short*)(ws + B_PCT);
  unsigned short* WB = (unsigned short*)(ws + B_WB);
  int idx = blockIdx.x*256 + threadIdx.x;
  if (idx < 4194304){
    WM[idx] = f2bf(wmat[idx]);            // [m][l][k] direct, m<128
  } else if (idx < 6291456){
    int j = idx - 4194304;                // pctT[m][kp][l] = pct[m][l][kp]
    int m = j >> 14, kp = (j >> 7) & 127, l = j & 127;
    PT[j] = f2bf(pct[m*16384 + l*128 + kp]);
  } else if (idx < 6356992){
    int j = idx - 6291456;
    WB[j] = f2bf(Wc[j]);                  // [o][c]
  }
}

// ---------------- MFMA GEMM template (double-buffered pipeline) ---------------
// C[M][N] = A[M][K] * B_T[N][K]^T ; BM=MT*32, BN=NT*32, BK=32, 256 thr
// (2x2 waves, each wave (MT*16)x(NT*16) via 16x16x32 bf16 MFMA).
// Pipeline per K-step: issue global loads for step ks+1 (into regs) BEFORE the
// MFMAs of step ks; reg->LDS writes of ks+1 AFTER the MFMAs; ONE barrier/step.
// This gives each global load a full K-step of issue-to-use distance (T14/T3-min).
// AMODE 0: A fp32 -> quantize to bf16 in staging (BM must be 64)
// AMODE 1: A bf16 (pre-quantized)
// CMODE 0: row-major fp32 store (+optional bias[row])
// CMODE 1: transposed bf16 store C_T[col][row]
// CMODE 2: row-major bf16 store
// SKIP 1: skip nt-tiles with col_max < m (leg1, cols=l) ; SKIP 2: k-loop starts
//         at (m>>5) (leg2, k=l).  m = blockIdx.z>>1.
// WPE: min waves per EU hint.
template<int AMODE, int CMODE, bool BIAS, int MT, int NT, int SKIP, int WPE>
__global__ __launch_bounds__(256, WPE) void k_gemm(
    const float* __restrict__ Af,
    const unsigned short* __restrict__ Abf,
    const unsigned short* __restrict__ Bt,
    float* __restrict__ Cf,
    unsigned short* __restrict__ Cbf,
    const float* __restrict__ bias,
    int ldA, int ldB, int ldC, int ksteps,
    long long sA, long long sB, int bzsh, long long sC)
{
  constexpr int BM = MT*32;
  constexpr int BN = NT*32;
  __shared__ unsigned short As[2][BM][40];
  __shared__ unsigned short Bs[2][BN][40];
  const int tid = threadIdx.x;
  const int z = blockIdx.z;
  const int m = z >> 1;
  const long long offA = (long long)z * sA;
  const long long offB = (long long)(z >> bzsh) * sB;
  const long long offC = (long long)z * sC;
  const int row0 = blockIdx.x * BM;
  const int n0   = blockIdx.y * BN;
  const int lane = tid & 63;
  const int wv = tid >> 6;
  const int wm = wv >> 1, wn = wv & 1;
  const int fr = lane & 15, q = lane >> 4;

  // staging register state (in-flight tile)
  float   av[8];                       // AMODE0 payload (BM==64)
  ushort8 ar0, ar1, ar2, ar3;          // AMODE1 payload (up to 32 bf16)
  ushort8 br0, br1, br2, br3;          // B payload (up to 32 bf16)

  auto loadA = [&](int ks){
    const int k0 = ks * 32;
    if (AMODE == 0){                   // BM==64: row=tid>>2, 8 f32 each
      const int row = tid >> 2, qt = tid & 3;
      const float* s = Af + offA + (long long)(row0 + row) * ldA + k0 + qt*8;
      *(float4*)(av+0) = *(const float4*)(s+0);
      *(float4*)(av+4) = *(const float4*)(s+4);
    } else if (BM == 256){
      const unsigned short* s = Abf + offA + (long long)(row0 + tid) * ldA + k0;
      ar0 = *(const ushort8*)(s);    ar1 = *(const ushort8*)(s+8);
      ar2 = *(const ushort8*)(s+16); ar3 = *(const ushort8*)(s+24);
    } else if (BM == 128){
      const int row = tid >> 1, half = tid & 1;
      const unsigned short* s = Abf + offA + (long long)(row0 + row) * ldA + k0 + half*16;
      ar0 = *(const ushort8*)(s); ar1 = *(const ushort8*)(s+8);
    } else {                           // BM==64
      const int row = tid >> 2, qt = tid & 3;
      const unsigned short* s = Abf + offA + (long long)(row0 + row) * ldA + k0 + qt*8;
      ar0 = *(const ushort8*)(s);
    }
  };
  auto writeA = [&](int buf){
    if (AMODE == 0){
      const int row = tid >> 2, qt = tid & 3;
      ushort8 H;
#pragma unroll
      for (int j=0;j<8;++j) H[j] = f2bf(av[j]);
      *(ushort8*)&As[buf][row][qt*8] = H;
    } else if (BM == 256){
      *(ushort8*)&As[buf][tid][0]  = ar0;
      *(ushort8*)&As[buf][tid][8]  = ar1;
      *(ushort8*)&As[buf][tid][16] = ar2;
      *(ushort8*)&As[buf][tid][24] = ar3;
    } else if (BM == 128){
      const int row = tid >> 1, half = tid & 1;
      *(ushort8*)&As[buf][row][half*16]   = ar0;
      *(ushort8*)&As[buf][row][half*16+8] = ar1;
    } else {
      const int row = tid >> 2, qt = tid & 3;
      *(ushort8*)&As[buf][row][qt*8] = ar0;
    }
  };
  auto loadB = [&](int ks){
    const int k0 = ks * 32;
    if (BN == 256){
      const unsigned short* s = Bt + offB + (long long)(n0 + tid) * ldB + k0;
      br0 = *(const ushort8*)(s);    br1 = *(const ushort8*)(s+8);
      br2 = *(const ushort8*)(s+16); br3 = *(const ushort8*)(s+24);
    } else if (BN == 128){
      const int row = tid >> 1, half = tid & 1;
      const unsigned short* s = Bt + offB + (long long)(n0 + row) * ldB + k0 + half*16;
      br0 = *(const ushort8*)(s); br1 = *(const ushort8*)(s+8);
    } else {                           // BN==64
      const int row = tid >> 2, qt = tid & 3;
      const unsigned short* s = Bt + offB + (long long)(n0 + row) * ldB + k0 + qt*8;
      br0 = *(const ushort8*)(s);
    }
  };
  auto writeB = [&](int buf){
    if (BN == 256){
      *(ushort8*)&Bs[buf][tid][0]  = br0;
      *(ushort8*)&Bs[buf][tid][8]  = br1;
      *(ushort8*)&Bs[buf][tid][16] = br2;
      *(ushort8*)&Bs[buf][tid][24] = br3;
    } else if (BN == 128){
      const int row = tid >> 1, half = tid & 1;
      *(ushort8*)&Bs[buf][row][half*16]   = br0;
      *(ushort8*)&Bs[buf][row][half*16+8] = br1;
    } else {
      const int row = tid >> 2, qt = tid & 3;
      *(ushort8*)&Bs[buf][row][qt*8] = br0;
    }
  };

  f32x4 acc[MT][NT];
#pragma unroll
  for (int i=0;i<MT;++i)
#pragma unroll
    for (int j=0;j<NT;++j) acc[i][j] = (f32x4){0.f,0.f,0.f,0.f};

  const int ks0 = (SKIP == 2) ? (m >> 5) : 0;

  // prologue: stage first tile into buf 0
  loadA(ks0); loadB(ks0);
  writeA(0);  writeB(0);
  __syncthreads();

  int cur = 0;
  for (int ks = ks0; ks < ksteps; ++ks){
    const bool more = (ks + 1 < ksteps);
    if (more){ loadA(ks+1); loadB(ks+1); }   // issue early: full step of latency hiding
    bf16x8 ah[MT];
#pragma unroll
    for (int mt=0;mt<MT;++mt)
      ah[mt] = *(const bf16x8*)&As[cur][wm*(MT*16)+mt*16+fr][q*8];
#pragma unroll
    for (int nt=0;nt<NT;++nt){
      if (SKIP == 1 && (wn*(NT*16) + nt*16 + 16 <= m)) continue;
      bf16x8 bb = *(const bf16x8*)&Bs[cur][wn*(NT*16)+nt*16+fr][q*8];
#pragma unroll
      for (int mt=0;mt<MT;++mt)
        acc[mt][nt] = __builtin_amdgcn_mfma_f32_16x16x32_bf16(ah[mt], bb, acc[mt][nt], 0,0,0);
    }
    if (more){
      writeA(cur^1); writeB(cur^1);          // write late (other buffer: no WAR hazard)
      __syncthreads();                       // one barrier per K-step
      cur ^= 1;
    }
  }

  if (CMODE == 0){
#pragma unroll
    for (int mt=0;mt<MT;++mt){
      int row = row0 + wm*(MT*16) + mt*16 + q*4;
      float bv0=0.f,bv1=0.f,bv2=0.f,bv3=0.f;
      if (BIAS){ bv0=bias[row]; bv1=bias[row+1]; bv2=bias[row+2]; bv3=bias[row+3]; }
#pragma unroll
      for (int nt=0;nt<NT;++nt){
        int col = n0 + wn*(NT*16) + nt*16 + fr;
        float* dst = Cf + offC + (long long)row * ldC + col;
        dst[0]                = acc[mt][nt][0] + bv0;
        dst[(long long)ldC]   = acc[mt][nt][1] + bv1;
        dst[(long long)ldC*2] = acc[mt][nt][2] + bv2;
        dst[(long long)ldC*3] = acc[mt][nt][3] + bv3;
      }
    }
  } else if (CMODE == 1){
#pragma unroll
    for (int nt=0;nt<NT;++nt){
      int colp = n0 + wn*(NT*16) + nt*16 + fr;
#pragma unroll
      for (int mt=0;mt<MT;++mt){
        int rowb = row0 + wm*(MT*16) + mt*16 + q*4;
        ushort4v h;
        h[0] = f2bf(acc[mt][nt][0]);
        h[1] = f2bf(acc[mt][nt][1]);
        h[2] = f2bf(acc[mt][nt][2]);
        h[3] = f2bf(acc[mt][nt][3]);
        *(ushort4v*)&Cbf[offC + (long long)colp * ldC + rowb] = h;
      }
    }
  } else {
#pragma unroll
    for (int mt=0;mt<MT;++mt){
      int row = row0 + wm*(MT*16) + mt*16 + q*4;
#pragma unroll
      for (int nt=0;nt<NT;++nt){
        int col = n0 + wn*(NT*16) + nt*16 + fr;
        unsigned short* dst = Cbf + offC + (long long)row * ldC + col;
        dst[0]      = f2bf(acc[mt][nt][0]);
        dst[ldC]    = f2bf(acc[mt][nt][1]);
        dst[ldC*2]  = f2bf(acc[mt][nt][2]);
        dst[ldC*3]  = f2bf(acc[mt][nt][3]);
      }
    }
  }
}

// ------- transpose bf16 g[256 p][65536 r] -> gT[65536 r][256 p] ---------------
__global__ __launch_bounds__(256) void k_trb(const unsigned short* __restrict__ g,
                                             unsigned short* __restrict__ gT){
  __shared__ unsigned short t[64][68];
  const int r0 = blockIdx.x * 64;
  const int p0 = blockIdx.y * 64;
  const int tr = threadIdx.x & 15, tc = threadIdx.x >> 4;
#pragma unroll
  for (int i=0;i<4;++i){
    int pl = tc + i*16;
    ushort4v v = *(const ushort4v*)(g + (long long)(p0+pl)*ROWS_LO + r0 + tr*4);
    *(ushort4v*)&t[pl][tr*4] = v;
  }
  __syncthreads();
#pragma unroll
  for (int i=0;i<4;++i){
    int rl = tc + i*16;
    ushort4v w;
    w[0]=t[tr*4+0][rl]; w[1]=t[tr*4+1][rl]; w[2]=t[tr*4+2][rl]; w[3]=t[tr*4+3][rl];
    *(ushort4v*)(gT + (long long)(r0+rl)*256 + p0 + tr*4) = w;
  }
}

// ------- transpose y[b][256 c][32768 s] f32 -> yT[b][s][c] bf16 ---------------
__global__ __launch_bounds__(256) void k_tr2(const float* __restrict__ y,
                                             unsigned short* __restrict__ yT){
  __shared__ float t[64][65];
  const int s0 = blockIdx.x * 64;
  const int c0 = blockIdx.y * 64;
  const int b  = blockIdx.z;
  const int tr = threadIdx.x & 15, tc = threadIdx.x >> 4;
#pragma unroll
  for (int i=0;i<4;++i){
    int cl = tc + i*16;
    float4 v = *(const float4*)(y + (long long)b*8388608 + (long long)(c0+cl)*32768 + s0 + tr*4);
    t[cl][tr*4+0]=v.x; t[cl][tr*4+1]=v.y; t[cl][tr*4+2]=v.z; t[cl][tr*4+3]=v.w;
  }
  __syncthreads();
#pragma unroll
  for (int i=0;i<4;++i){
    int sl = tc + i*16;
    ushort4v w;
    w[0]=f2bf(t[tr*4+0][sl]); w[1]=f2bf(t[tr*4+1][sl]);
    w[2]=f2bf(t[tr*4+2][sl]); w[3]=f2bf(t[tr*4+3][sl]);
    *(ushort4v*)(yT + (long long)b*8388608 + (long long)(s0+sl)*256 + c0 + tr*4) = w;
  }
}

// ---------------- GroupNorm stats --------------------------------------------
__global__ __launch_bounds__(256) void k_stats(const float* __restrict__ h,
                                               float* __restrict__ stats){
  const int bg = blockIdx.y;
  const int j  = blockIdx.x;
  const int t  = threadIdx.x;
  const float* base = h + (long long)bg*262144 + j*8192;
  float s = 0.f, ss = 0.f;
#pragma unroll
  for (int i=0;i<8;++i){
    float4 v = *(const float4*)(base + i*1024 + t*4);
    s  += v.x + v.y + v.z + v.w;
    ss += v.x*v.x + v.y*v.y + v.z*v.z + v.w*v.w;
  }
#pragma unroll
  for (int off=32; off>0; off>>=1){
    s  += __shfl_down(s, off, 64);
    ss += __shfl_down(ss, off, 64);
  }
  __shared__ float red[8];
  int wid = t >> 6;
  if ((t & 63) == 0){ red[wid*2] = s; red[wid*2+1] = ss; }
  __syncthreads();
  if (t == 0){
    float S  = red[0]+red[2]+red[4]+red[6];
    float SS = red[1]+red[3]+red[5]+red[7];
    atomicAdd(&stats[bg*2+0], S);
    atomicAdd(&stats[bg*2+1], SS);
  }
}

// ---------------- normalize + affine + exact GELU ----------------------------
__global__ __launch_bounds__(256) void k_norm(float* __restrict__ out,
                                              const float* __restrict__ stats,
                                              const float* __restrict__ gamma,
                                              const float* __restrict__ beta){
  long long idx4 = ((long long)blockIdx.x*256 + threadIdx.x)*4;
  int o = (int)((idx4 >> 15) & 255);
  int b = (int)(idx4 >> 23);
  int bg = b*32 + (o >> 3);
  const float inv_n = 1.0f/262144.0f;
  float mean = stats[bg*2+0] * inv_n;
  float var  = stats[bg*2+1] * inv_n - mean*mean;
  float sc = rsqrtf(var + 1e-5f);
  float ga = gamma[o], be = beta[o];
  float4 v = *(float4*)(out + idx4);
  float t0 = (v.x - mean)*sc*ga + be;
  float t1 = (v.y - mean)*sc*ga + be;
  float t2 = (v.z - mean)*sc*ga + be;
  float t3 = (v.w - mean)*sc*ga + be;
  const float ISQ2 = 0.70710678118654752f;
  v.x = 0.5f*t0*(1.0f + erff(t0*ISQ2));
  v.y = 0.5f*t1*(1.0f + erff(t1*ISQ2));
  v.z = 0.5f*t2*(1.0f + erff(t2*ISQ2));
  v.w = 0.5f*t3*(1.0f + erff(t3*ISQ2));
  *(float4*)(out + idx4) = v;
}

extern "C" void kernel_launch(void* const* d_in, const int* in_sizes, int n_in,
                              void* d_out, int out_size, void* d_ws, size_t ws_size,
                              hipStream_t stream){
  const float* x      = (const float*)d_in[0];
  const float* conv_w = (const float*)d_in[1];
  const float* conv_b = (const float*)d_in[2];
  const float* gamma  = (const float*)d_in[3];
  const float* beta   = (const float*)d_in[4];
  const float* wmat   = (const float*)d_in[5];
  const float* pct    = (const float*)d_in[6];
  unsigned char* ws = (unsigned char*)d_ws;

  unsigned short* FT   = (unsigned short*)(ws + B_FT);
  unsigned short* FIT  = (unsigned short*)(ws + B_FIT);
  unsigned short* WM   = (unsigned short*)(ws + B_WM);
  unsigned short* PT   = (unsigned short*)(ws + B_PCT);
  unsigned short* WB   = (unsigned short*)(ws + B_WB);
  float*          stats= (float*)(ws + B_STATS);
  unsigned short* Xbf  = (unsigned short*)(ws + B_R1);  // [256 p][131072] bf16
  unsigned short* gb   = (unsigned short*)(ws + B_R1);  // [256 p][65536] bf16 (Xbf dead)
  float*          y    = (float*)(ws + B_R1);           // [65536][256] f32 (gb dead)
  unsigned short* flmb = (unsigned short*)(ws + B_R2);  // [256 p][512 bc][128 l] bf16
  unsigned short* gTb  = (unsigned short*)(ws + B_R2);  // [65536][256 p] bf16 (flmb dead)
  unsigned short* yT   = (unsigned short*)(ws + B_R2);  // [b][32768 s][256 c] bf16 (gTb dead)
  float* out = (float*)d_out;

  k_tables<<<769, 256, 0, stream>>>(ws);
  k_prep  <<<24832, 256, 0, stream>>>(wmat, pct, conv_w, ws);

  // DFT: A=x f32 [131072x512] (quantized in staging), B=F_T, C->Xbf trans bf16
  k_gemm<0,1,false,2,8,0,2><<<dim3(2048,1,1), 256, 0, stream>>>(
      x, nullptr, FT, nullptr, Xbf, nullptr, 512, 512, ROWS_HI, 16, 0, 0, 0, 0);
  // Leg1: per plane: A=Xbf[p] [512x256], B=WM[m] [128lx256k], C=flmb bf16; skip l<m tiles
  k_gemm<1,2,false,4,4,1,2><<<dim3(4,1,256), 256, 0, stream>>>(
      nullptr, Xbf, WM, nullptr, flmb, nullptr, 256, 256, 128, 8,
      131072LL, 32768LL, 1, 65536LL);
  // Leg2: per plane: A=flmb[p] [512x128], B=PT[m] [128k'x128l], C=gb bf16; k-start m>>5
  k_gemm<1,2,false,4,4,2,2><<<dim3(4,1,256), 256, 0, stream>>>(
      nullptr, flmb, PT, nullptr, gb, nullptr, 128, 128, 128, 4,
      65536LL, 16384LL, 1, 65536LL);
  // transpose gb -> gTb
  k_trb<<<dim3(1024,4), 256, 0, stream>>>(gb, gTb);
  // iDFT: A=gTb [65536x256], B=Fi_T [256w'x256p], C=y f32
  k_gemm<1,0,false,2,8,0,2><<<dim3(1024,1,1), 256, 0, stream>>>(
      nullptr, gTb, FIT, y, nullptr, nullptr, 256, 256, 256, 8, 0, 0, 0, 0);
  // transpose+quantize y -> yT bf16
  k_tr2<<<dim3(512,4,2), 256, 0, stream>>>(y, yT);
  // Conv: per b: A=WB [256x256], B=yT[b] [32768x256], C=out f32 +bias
  k_gemm<1,0,true,8,2,0,2><<<dim3(1,512,2), 256, 0, stream>>>(
      nullptr, WB, yT, out, nullptr, conv_b, 256, 256, 32768, 8,
      0, 8388608LL, 0, 8388608LL);

  k_stats<<<dim3(32,64), 256, 0, stream>>>(out, stats);
  k_norm <<<16384, 256, 0, stream>>>(out, stats, gamma, beta);
}